// Round 1
// 441.858 us; speedup vs baseline: 1.0440x; 1.0440x over previous
//
#include <hip/hip_runtime.h>

// out[b,c,n] = x[b,c, px*NY+py], px=trunc(clip(coords[b,n,1]*(NX-1),0,NX)),
//                                py=trunc(clip(coords[b,n,0]*(NY-1),0,NY))
//
// R4: R3 ran at ~2.3 TB/s effective vs a 646 MB / ~103 us roofline. Theory:
// 128B-granular transpose reads (32-pos tiles, 1024 interleaved plane-streams)
// and 256B gather stores. Fix: 128x128 tiles everywhere so every global
// transaction is >=512B:
//   transpose: float4 nontemporal reads of x (read-once; preserve xT in L3),
//              512B float2 coalesced writes of touched positions.
//   gather:    float4 reads (512B/sample channel vector), LDS transpose,
//              512B float2 nontemporal stores along n.
#define B_  8
#define C_  128
#define NX_ 256
#define NY_ 256
#define N_  32768
#define PLANE_ (NX_ * NY_)                       // 65536
#define XT_BYTES ((size_t)B_ * PLANE_ * C_ * 4)  // 268435456
#define BM_WORDS_PER_B (PLANE_ / 32)             // 2048
#define BM_BYTES ((size_t)B_ * BM_WORDS_PER_B * 4) // 65536

typedef float f32x4 __attribute__((ext_vector_type(4)));
typedef float f32x2 __attribute__((ext_vector_type(2)));

__device__ __forceinline__ int sample_idx(const float* __restrict__ coords, int b, int n) {
    const float2 cc = *reinterpret_cast<const float2*>(coords + ((size_t)b * N_ + n) * 2);
    const int px = (int)fminf(fmaxf(cc.y * (float)(NX_ - 1), 0.0f), (float)NX_);
    const int py = (int)fminf(fmaxf(cc.x * (float)(NY_ - 1), 0.0f), (float)NY_);
    return min(px * NY_ + py, PLANE_ - 1);
}

// ---- pass 0: mark touched positions ---------------------------------------
__global__ __launch_bounds__(256) void mark_kernel(const float* __restrict__ coords,
                                                   unsigned* __restrict__ bm) {
    const int n = blockIdx.x * 256 + threadIdx.x;
    const int b = blockIdx.y;
    const int idx = sample_idx(coords, b, n);
    atomicOr(&bm[b * BM_WORDS_PER_B + (idx >> 5)], 1u << (idx & 31));
}

// ---- pass 1: transpose (b,c,p) -> (b,p,c), touched positions only ---------
// 128 positions x 128 channels per block. Reads: 512B/channel-chunk (float4 x
// 32 lanes), nontemporal. Writes: 512B float2 stores, bitmap-masked.
__global__ __launch_bounds__(256, 2) void transpose_kernel(const float* __restrict__ x,
                                                           const unsigned* __restrict__ bm,
                                                           float* __restrict__ xT) {
    __shared__ float tile[128][130];             // [p][c], pad 130: b64 reads 4-way (ok)
    const int bid = blockIdx.x;
    const int b   = bid & 7;                     // XCD spread
    const int p0  = (bid >> 3) << 7;             // 128 positions per block
    const int t   = threadIdx.x;
    const int w   = t >> 6, l = t & 63;
    const int q   = l & 31, h = l >> 5;          // q: 16B chunk, h: channel parity

    const float* __restrict__ xb = x + (size_t)b * C_ * PLANE_ + p0;
    #pragma unroll
    for (int r = 0; r < 16; ++r) {               // c = 0..127, p = 0..127
        const int c = r * 8 + w * 2 + h;
        const f32x4 v = __builtin_nontemporal_load(
            reinterpret_cast<const f32x4*>(xb + (size_t)c * PLANE_ + 4 * q));
        #pragma unroll
        for (int j = 0; j < 4; ++j) tile[4 * q + j][c] = v[j];
    }
    __syncthreads();

    float* __restrict__ xTb = xT + (size_t)b * PLANE_ * C_;
    const unsigned* __restrict__ bmb = bm + b * BM_WORDS_PER_B + (p0 >> 5);
    #pragma unroll
    for (int r = 0; r < 32; ++r) {
        const int p = r * 4 + w;                 // wave-uniform -> uniform branch
        if (bmb[p >> 5] & (1u << (p & 31))) {
            const f32x2 v2 = *reinterpret_cast<const f32x2*>(&tile[p][2 * l]);
            *reinterpret_cast<f32x2*>(&xTb[(size_t)(p0 + p) * C_ + 2 * l]) = v2;
        }
    }
}

// ---- pass 2: gather 128 samples x 128 channels per block ------------------
// Reads: 512B/sample (float4 x 32 lanes, 2 samples per instruction).
// Stores: 512B float2 nontemporal per channel row.
__global__ __launch_bounds__(256, 2) void gather_kernel(const float* __restrict__ xT,
                                                        const float* __restrict__ coords,
                                                        float* __restrict__ out) {
    __shared__ float smp[C_][130];               // [c][s], pad 130
    __shared__ int   sidx[128];
    const int bid = blockIdx.x;
    const int b   = bid & 7;                     // XCD-affine batch
    const int n0  = (bid >> 3) << 7;             // 128 samples per block
    const int t   = threadIdx.x;
    const int w   = t >> 6, l = t & 63;
    const int cq  = l & 31, sh = l >> 5;         // cq: 16B channel chunk, sh: sample parity

    if (t < 128) sidx[t] = sample_idx(coords, b, n0 + t);
    __syncthreads();

    const float* __restrict__ xTb = xT + (size_t)b * PLANE_ * C_;
    #pragma unroll
    for (int r = 0; r < 16; ++r) {               // s = 0..127
        const int s = r * 8 + w * 2 + sh;
        const f32x4 v = *reinterpret_cast<const f32x4*>(xTb + (size_t)sidx[s] * C_ + 4 * cq);
        #pragma unroll
        for (int j = 0; j < 4; ++j) smp[4 * cq + j][s] = v[j];
    }
    __syncthreads();

    float* __restrict__ ob = out + (size_t)b * C_ * N_ + n0;
    #pragma unroll
    for (int r = 0; r < 32; ++r) {               // c = 0..127
        const int c = r * 4 + w;
        const f32x2 v2 = *reinterpret_cast<const f32x2*>(&smp[c][2 * l]);
        __builtin_nontemporal_store(v2, reinterpret_cast<f32x2*>(ob + (size_t)c * N_ + 2 * l));
    }
}

// ---- fallback (R2): direct gather, used only if ws too small --------------
__global__ __launch_bounds__(256) void fallback_kernel(const float* __restrict__ x,
                                                       const float* __restrict__ coords,
                                                       float* __restrict__ out) {
    const int bid  = blockIdx.x;
    const int b    = bid & 7;
    const int rem  = bid >> 3;
    const int cg   = rem >> 7;
    const int nblk = rem & 127;
    const int n  = nblk * 256 + threadIdx.x;
    const int c0 = cg * 8;
    const int idx = sample_idx(coords, b, n);
    const float* __restrict__ xb = x + ((size_t)b * C_ + c0) * PLANE_ + idx;
    float* __restrict__ ob = out + ((size_t)b * C_ + c0) * N_ + n;
    #pragma unroll
    for (int i = 0; i < 8; ++i)
        __builtin_nontemporal_store(xb[(size_t)i * PLANE_], ob + (size_t)i * N_);
}

extern "C" void kernel_launch(void* const* d_in, const int* in_sizes, int n_in,
                              void* d_out, int out_size, void* d_ws, size_t ws_size,
                              hipStream_t stream) {
    const float* x      = (const float*)d_in[0];
    const float* coords = (const float*)d_in[1];
    float* out          = (float*)d_out;

    if (ws_size >= XT_BYTES + BM_BYTES) {
        float*    xT = (float*)d_ws;
        unsigned* bm = (unsigned*)((char*)d_ws + XT_BYTES);
        hipMemsetAsync(bm, 0, BM_BYTES, stream);
        mark_kernel<<<dim3(N_ / 256, B_), 256, 0, stream>>>(coords, bm);
        transpose_kernel<<<B_ * (PLANE_ / 128), 256, 0, stream>>>(x, bm, xT);
        gather_kernel<<<B_ * (N_ / 128), 256, 0, stream>>>(xT, coords, out);
    } else {
        fallback_kernel<<<B_ * 16 * 128, 256, 0, stream>>>(x, coords, out);
    }
}